// Round 6
// baseline (287.417 us; speedup 1.0000x reference)
//
#include <hip/hip_runtime.h>
#include <hip/hip_bf16.h>
#include <math.h>

// Problem: B=2, S=2048, D=1024, H=16, dk=64. fp32 in/out, bf16 MFMA compute.
#define NUM_HEADS 16
#define DK 64
#define SEQ 2048
#define BATCHN 2
#define DM 1024
#define BS (BATCHN*SEQ)          // 4096
#define LSCALE 0.18033688011112042f   // 0.125 * log2(e), folded into Q

typedef __bf16 bf16x8 __attribute__((ext_vector_type(8)));
typedef float floatx4 __attribute__((ext_vector_type(4)));
typedef unsigned short ushort;
typedef unsigned int uint;

__device__ __forceinline__ ushort f2bu(float f){
    union { __hip_bfloat16 h; ushort u; } cv; cv.h = __float2bfloat16(f); return cv.u;
}
__device__ __forceinline__ uint packbf(float a, float b){
    return (uint)f2bu(a) | ((uint)f2bu(b) << 16);
}

// ---------------------------------------------------------------------------
// Fused fp32->bf16 casts: x (2048 blocks), Wq,Wk (into Wqk concat), Wv, Wo.
// ---------------------------------------------------------------------------
__global__ __launch_bounds__(256)
void castall(const float* __restrict__ x,  const float* __restrict__ wq,
             const float* __restrict__ wk, const float* __restrict__ wv,
             const float* __restrict__ wo, ushort* __restrict__ xb,
             ushort* __restrict__ wqkb, ushort* __restrict__ wvb,
             ushort* __restrict__ wob)
{
    int bid = blockIdx.x;
    const float* src; ushort* dst; int off;
    if (bid < 2048)      { src = x;  dst = xb;             off = bid; }
    else if (bid < 2560) { src = wq; dst = wqkb;           off = bid - 2048; }
    else if (bid < 3072) { src = wk; dst = wqkb + 1048576; off = bid - 2560; }
    else if (bid < 3584) { src = wv; dst = wvb;            off = bid - 3072; }
    else                 { src = wo; dst = wob;            off = bid - 3584; }
    int i = off*2048 + threadIdx.x*8;
    float4 a = *(const float4*)(src+i);
    float4 b = *(const float4*)(src+i+4);
    uint4 o;
    o.x = packbf(a.x, a.y);
    o.y = packbf(a.z, a.w);
    o.z = packbf(b.x, b.y);
    o.w = packbf(b.z, b.w);
    *(uint4*)(dst+i) = o;
}

// RoPE table: tab[s*32+i] = (cos, sin) of pos[s] * 10000^(-i/32)
__global__ __launch_bounds__(256) void ropek(const int* __restrict__ pos,
                                             float2* __restrict__ tab){
    int idx = blockIdx.x*256 + threadIdx.x;
    if (idx >= SEQ*32) return;
    int s = idx >> 5, i = idx & 31;
    float invf = expf(-0.28782313662425575f * (float)i);  // ln(1e4)/32
    float ang = (float)pos[s] * invf;
    float sn, cs; sincosf(ang, &sn, &cs);
    tab[idx] = make_float2(cs, sn);
}

// ---------------------------------------------------------------------------
// Fused projections (one dispatch, 1536 blocks):
//   blocks 0..1023 : QK proj, C = x·[Wq;Wk]^T, RoPE, scatter [b,h,s,64];
//                    Q additionally scaled by LSCALE (folded softmax scale).
//   blocks 1024..1535 : V^T proj, C = Wv·x^T row-major [1024, 4096].
// Tile 128(M)x64(N), BK=32, 4 waves.
// ---------------------------------------------------------------------------
__global__ __launch_bounds__(256)
void proj_fused(const ushort* __restrict__ xb, const ushort* __restrict__ Wqkb,
                const ushort* __restrict__ Wvb, ushort* __restrict__ Qb,
                ushort* __restrict__ VTp, const float2* __restrict__ rope)
{
    __shared__ ushort As[128][40];
    __shared__ ushort Bs[64][40];

    const int bid = blockIdx.x;
    const ushort* A; const ushort* W; int row0, col0, mode;
    if (bid < 1024) { A = xb;  W = Wqkb; row0 = (bid >> 5) * 128;
                      col0 = (bid & 31) * 64;  mode = 1; }
    else            { int i = bid - 1024; A = Wvb; W = xb;
                      row0 = (i >> 6) * 128; col0 = (i & 63) * 64; mode = 2; }

    const int t = threadIdx.x;
    const int w = t >> 6;
    const int L = t & 63;
    const int lr = L & 15;
    const int lq = L >> 4;
    const int wrow = w * 32;

    floatx4 acc[2][4];
    #pragma unroll
    for (int i = 0; i < 2; ++i)
        #pragma unroll
        for (int j = 0; j < 4; ++j)
            acc[i][j] = (floatx4){0.f,0.f,0.f,0.f};

    const int rr = t >> 2, ko = (t & 3) * 8;

    for (int k0 = 0; k0 < DM; k0 += 32) {
        const ushort* ap = A + (size_t)(row0 + rr) * DM + k0 + ko;
        uint4 va  = *(const uint4*)ap;
        uint4 va2 = *(const uint4*)(ap + (size_t)64 * DM);
        const ushort* wp = W + (size_t)(col0 + rr) * DM + k0 + ko;
        uint4 vb  = *(const uint4*)wp;
        *(uint4*)&As[rr][ko]      = va;
        *(uint4*)&As[rr + 64][ko] = va2;
        *(uint4*)&Bs[rr][ko]      = vb;
        __syncthreads();

        bf16x8 aF0 = *(const bf16x8*)&As[wrow + lr][lq*8];
        bf16x8 aF1 = *(const bf16x8*)&As[wrow + 16 + lr][lq*8];
        #pragma unroll
        for (int tc = 0; tc < 4; ++tc) {
            bf16x8 bF = *(const bf16x8*)&Bs[tc*16 + lr][lq*8];
            acc[0][tc] = __builtin_amdgcn_mfma_f32_16x16x32_bf16(aF0, bF, acc[0][tc], 0, 0, 0);
            acc[1][tc] = __builtin_amdgcn_mfma_f32_16x16x32_bf16(aF1, bF, acc[1][tc], 0, 0, 0);
        }
        __syncthreads();
    }

    // C layout: col = col0 + tc*16 + lr, row = row0+wrow+tr*16+lq*4+r
    if (mode == 2) {
        #pragma unroll
        for (int tr = 0; tr < 2; ++tr)
            #pragma unroll
            for (int tc = 0; tc < 4; ++tc)
                #pragma unroll
                for (int r = 0; r < 4; ++r) {
                    int m = row0 + wrow + tr*16 + lq*4 + r;
                    int c = col0 + tc*16 + lr;
                    VTp[(size_t)m * BS + c] = f2bu(acc[tr][tc][r]);
                }
    } else {
        const int mat = col0 >> 10;             // 0 = Q, 1 = K
        const int hh  = (col0 & 1023) >> 6;
        ushort* out = Qb + (size_t)mat * (BATCHN*NUM_HEADS*SEQ*DK);
        const float qscale = mat ? 1.f : LSCALE;
        #pragma unroll
        for (int tr = 0; tr < 2; ++tr)
            #pragma unroll
            for (int tc = 0; tc < 4; ++tc)
                #pragma unroll
                for (int r = 0; r < 4; ++r) {
                    int m = row0 + wrow + tr*16 + lq*4 + r;
                    int b = m >> 11;
                    int s = m & (SEQ - 1);
                    int dd = ((col0 & 63) + tc*16 + lr) & 63;
                    float v = acc[tr][tc][r];
                    float o = __shfl_xor(v, 1, 64);
                    float2 cs = rope[s*32 + (dd >> 1)];
                    float rv = (dd & 1) ? fmaf(o, cs.y,  v * cs.x)
                                        : fmaf(-o, cs.y, v * cs.x);
                    out[((size_t)((b*NUM_HEADS + hh)*SEQ + s))*DK + dd] =
                        f2bu(rv * qscale);
                }
    }
}

// ---------------------------------------------------------------------------
// Out projection: out[m,n] = sum_k attnb[m,k]*Wo[n,k], fp32 out. grid (16,32).
// ---------------------------------------------------------------------------
__global__ __launch_bounds__(256)
void gemm_out(const ushort* __restrict__ A, const ushort* __restrict__ W,
              float* __restrict__ out)
{
    __shared__ ushort As[128][40];
    __shared__ ushort Bs[64][40];

    const int t = threadIdx.x;
    const int w = t >> 6;
    const int L = t & 63;
    const int lr = L & 15;
    const int lq = L >> 4;
    const int row0 = blockIdx.y * 128;
    const int col0 = blockIdx.x * 64;
    const int wrow = w * 32;

    floatx4 acc[2][4];
    #pragma unroll
    for (int i = 0; i < 2; ++i)
        #pragma unroll
        for (int j = 0; j < 4; ++j)
            acc[i][j] = (floatx4){0.f,0.f,0.f,0.f};

    const int rr = t >> 2, ko = (t & 3) * 8;

    for (int k0 = 0; k0 < DM; k0 += 32) {
        const ushort* ap = A + (size_t)(row0 + rr) * DM + k0 + ko;
        uint4 va  = *(const uint4*)ap;
        uint4 va2 = *(const uint4*)(ap + (size_t)64 * DM);
        const ushort* wp = W + (size_t)(col0 + rr) * DM + k0 + ko;
        uint4 vb  = *(const uint4*)wp;
        *(uint4*)&As[rr][ko]      = va;
        *(uint4*)&As[rr + 64][ko] = va2;
        *(uint4*)&Bs[rr][ko]      = vb;
        __syncthreads();

        bf16x8 aF0 = *(const bf16x8*)&As[wrow + lr][lq*8];
        bf16x8 aF1 = *(const bf16x8*)&As[wrow + 16 + lr][lq*8];
        #pragma unroll
        for (int tc = 0; tc < 4; ++tc) {
            bf16x8 bF = *(const bf16x8*)&Bs[tc*16 + lr][lq*8];
            acc[0][tc] = __builtin_amdgcn_mfma_f32_16x16x32_bf16(aF0, bF, acc[0][tc], 0, 0, 0);
            acc[1][tc] = __builtin_amdgcn_mfma_f32_16x16x32_bf16(aF1, bF, acc[1][tc], 0, 0, 0);
        }
        __syncthreads();
    }

    #pragma unroll
    for (int tr = 0; tr < 2; ++tr)
        #pragma unroll
        for (int tc = 0; tc < 4; ++tc)
            #pragma unroll
            for (int r = 0; r < 4; ++r) {
                int m = row0 + wrow + tr*16 + lq*4 + r;
                int c = col0 + tc*16 + lr;
                out[(size_t)m * DM + c] = acc[tr][tc][r];
            }
}

// ---------------------------------------------------------------------------
// Flash attention, bf16 MFMA, no-max softmax, TRANSPOSED QK (S^T = K·Q^T):
// lane's 4 accum regs = 4 consecutive keys for one q -> in-lane bf16 pair
// packing, ds_write_b64, no per-element shuffles. K/V next-tile prefetch in
// registers. Q pre-scaled by LSCALE at projection. Block: 4 waves x 16 q.
// grid.x=48 per (h,b): qt<16 -> 1 block; qt>=16 -> 2 chunks (combine()).
// ---------------------------------------------------------------------------
__global__ __launch_bounds__(256)
void attn_mfma(const ushort* __restrict__ Qb, const ushort* __restrict__ Kb,
               const ushort* __restrict__ VT, ushort* __restrict__ attnb,
               float* __restrict__ Opart, float* __restrict__ lpart)
{
    __shared__ ushort Ks[128][72];     // [key][dim]
    __shared__ ushort Vs[64][136];     // [dim][key]
    __shared__ ushort Ps[4][16][136];  // per-wave P[q][key]

    const int t = threadIdx.x;
    const int w = t >> 6;
    const int L = t & 63;
    const int lr = L & 15, lq = L >> 4;
    const int h  = blockIdx.y;
    const int b  = blockIdx.z;

    int qt, t0, t1, chunk = 0; bool split;
    {
        const int bx = blockIdx.x;   // 0..47
        if (bx < 16) { qt = bx; t0 = 0; t1 = (qt >> 1) + 1; split = false; }
        else {
            int c2 = bx - 16; qt = 16 + (c2 >> 1); chunk = c2 & 1;
            int nt = (qt >> 1) + 1, half = nt >> 1;
            t0 = chunk ? half : 0; t1 = chunk ? nt : half; split = true;
        }
    }
    const int ntfull = (qt >> 1) + 1;
    const int q0 = qt * 64;
    const int qw = q0 + w * 16;
    const int qmax = q0 + 63;
    const size_t qkbase = (size_t)(b*NUM_HEADS + h) * SEQ * DK;

    bf16x8 qF0, qF1;
    {
        const ushort* qp = Qb + qkbase + (size_t)(qw + lr) * DK + lq*8;
        qF0 = *(const bf16x8*)qp;
        qF1 = *(const bf16x8*)(qp + 32);
    }

    floatx4 O[4];
    #pragma unroll
    for (int g = 0; g < 4; ++g) O[g] = (floatx4){0.f,0.f,0.f,0.f};
    float l_lane = 0.f;

    const int kr = t >> 3, kc8 = (t & 7) * 8;
    const int vr = t >> 4, vc8 = (t & 15) * 8;
    const ushort* kp0 = Kb + qkbase + (size_t)kr * DK + kc8;
    const ushort* vp0 = VT + ((size_t)(h*DK + vr)) * BS + b*SEQ + vc8;

    uint4 kv[4], vv[4];
    {
        const int kb = t0 * 128;
        #pragma unroll
        for (int c = 0; c < 4; ++c) {
            kv[c] = *(const uint4*)(kp0 + (size_t)(kb + 32*c) * DK);
            vv[c] = *(const uint4*)(vp0 + (size_t)(16*c) * BS + kb);
        }
    }

    for (int tile = t0; tile < t1; ++tile) {
        __syncthreads();
        #pragma unroll
        for (int c = 0; c < 4; ++c) {
            *(uint4*)&Ks[32*c + kr][kc8] = kv[c];
            *(uint4*)&Vs[16*c + vr][vc8] = vv[c];
        }
        __syncthreads();
        if (tile + 1 < t1) {     // prefetch next tile; overlapped with compute
            const int kb2 = (tile + 1) * 128;
            #pragma unroll
            for (int c = 0; c < 4; ++c) {
                kv[c] = *(const uint4*)(kp0 + (size_t)(kb2 + 32*c) * DK);
                vv[c] = *(const uint4*)(vp0 + (size_t)(16*c) * BS + kb2);
            }
        }

        const int kb = tile * 128;
        const int nc = min(4, ((qmax - kb) >> 5) + 1);  // active 32-key chunks
        const int ng = nc * 2;
        const bool lastt = (tile == ntfull - 1);
        const int lim = qw + lr - kb;                   // key offset <= lim ok

        #pragma unroll
        for (int g = 0; g < 8; ++g)
            if (g < ng) {
                floatx4 s = (floatx4){0.f,0.f,0.f,0.f};
                bf16x8 kf0 = *(const bf16x8*)&Ks[g*16 + lr][lq*8];
                bf16x8 kf1 = *(const bf16x8*)&Ks[g*16 + lr][32 + lq*8];
                // S^T = K·Q^T: lane -> q = qw+lr (col), key = kb+g*16+lq*4+r (row)
                s = __builtin_amdgcn_mfma_f32_16x16x32_bf16(kf0, qF0, s, 0, 0, 0);
                s = __builtin_amdgcn_mfma_f32_16x16x32_bf16(kf1, qF1, s, 0, 0, 0);
                float p0, p1, p2, p3;
                if (lastt) {
                    const int kbase = g*16 + lq*4;
                    p0 = (kbase + 0 <= lim) ? exp2f(s[0]) : 0.f;
                    p1 = (kbase + 1 <= lim) ? exp2f(s[1]) : 0.f;
                    p2 = (kbase + 2 <= lim) ? exp2f(s[2]) : 0.f;
                    p3 = (kbase + 3 <= lim) ? exp2f(s[3]) : 0.f;
                } else {
                    p0 = exp2f(s[0]); p1 = exp2f(s[1]);
                    p2 = exp2f(s[2]); p3 = exp2f(s[3]);
                }
                l_lane += (p0 + p1) + (p2 + p3);
                uint2 pk;
                pk.x = packbf(p0, p1);
                pk.y = packbf(p2, p3);
                *(uint2*)&Ps[w][lr][g*16 + lq*4] = pk;
            }
        asm volatile("s_waitcnt lgkmcnt(0)" ::: "memory");

        #pragma unroll
        for (int c = 0; c < 4; ++c)
            if (c < nc) {
                bf16x8 pF = *(const bf16x8*)&Ps[w][lr][c*32 + lq*8];
                #pragma unroll
                for (int g2 = 0; g2 < 4; ++g2) {
                    bf16x8 vf = *(const bf16x8*)&Vs[g2*16 + lr][c*32 + lq*8];
                    O[g2] = __builtin_amdgcn_mfma_f32_16x16x32_bf16(pF, vf, O[g2], 0, 0, 0);
                }
            }
    }

    // l for q=qw+lr: sum across the 4 lq lanes sharing lr
    l_lane += __shfl_xor(l_lane, 16, 64);
    l_lane += __shfl_xor(l_lane, 32, 64);

    if (!split) {
        #pragma unroll
        for (int r = 0; r < 4; ++r) {
            float lv = __shfl(l_lane, lq*4 + r, 64);   // l for q row lq*4+r
            float li = 1.f / lv;
            int s = qw + lq*4 + r;
            #pragma unroll
            for (int g2 = 0; g2 < 4; ++g2)
                attnb[((size_t)(b*SEQ + s))*DM + h*DK + g2*16 + lr] = f2bu(O[g2][r] * li);
        }
    } else {
        const size_t tb = (size_t)((b*NUM_HEADS + h)*16 + (qt - 16)) * 2 + chunk;
        float* Op = Opart + tb * 4096;
        #pragma unroll
        for (int r = 0; r < 4; ++r) {
            int ql = w*16 + lq*4 + r;
            #pragma unroll
            for (int g2 = 0; g2 < 4; ++g2)
                Op[ql*64 + g2*16 + lr] = O[g2][r];
        }
        if (lq == 0) lpart[tb*64 + w*16 + lr] = l_lane;
    }
}

// ---------------------------------------------------------------------------
// Combine: for qt>=16, O = (O0+O1)/(l0+l1) -> attnb bf16. 512 blocks.
// ---------------------------------------------------------------------------
__global__ __launch_bounds__(256)
void combine(const float* __restrict__ Opart, const float* __restrict__ lpart,
             ushort* __restrict__ attnb)
{
    int gx = blockIdx.x;            // 512 = 32 (b,h) x 16 qt
    int qti = gx & 15, bh = gx >> 4;
    int h = bh & 15, b = bh >> 4;
    int qt = 16 + qti;
    int tid = threadIdx.x;
    int row = tid >> 2, c0 = (tid & 3) * 16;
    size_t tb = (size_t)(bh*16 + qti) * 2;
    const float* O0 = Opart + tb*4096 + row*64 + c0;
    const float* O1 = O0 + 4096;
    float l = lpart[tb*64 + row] + lpart[tb*64 + 64 + row];
    float li = 1.f / l;
    int s = qt*64 + row;
    ushort* dst = attnb + ((size_t)(b*SEQ + s))*DM + h*DK + c0;
    #pragma unroll
    for (int e = 0; e < 16; e += 4) {
        float4 a = *(const float4*)(O0 + e);
        float4 c = *(const float4*)(O1 + e);
        dst[e+0] = f2bu((a.x + c.x) * li);
        dst[e+1] = f2bu((a.y + c.y) * li);
        dst[e+2] = f2bu((a.z + c.z) * li);
        dst[e+3] = f2bu((a.w + c.w) * li);
    }
}

// ---------------------------------------------------------------------------
extern "C" void kernel_launch(void* const* d_in, const int* in_sizes, int n_in,
                              void* d_out, int out_size, void* d_ws, size_t ws_size,
                              hipStream_t stream) {
    const float* x   = (const float*)d_in[0];
    const float* Wq  = (const float*)d_in[1];
    const float* Wk  = (const float*)d_in[2];
    const float* Wv  = (const float*)d_in[3];
    const float* Wo  = (const float*)d_in[4];
    const int*   pos = (const int*)d_in[5];
    float* out = (float*)d_out;

    const size_t MB = 1u << 20;
    char* ws = (char*)d_ws;
    // xb/Wqkb/Wvb dead after projections; Opart (16 MB) aliases them.
    ushort* xb    = (ushort*)(ws);             //  8 MB  [4096,1024]
    ushort* Wqkb  = (ushort*)(ws +  8*MB);     //  4 MB  [Wq;Wk]
    ushort* Wvb   = (ushort*)(ws + 12*MB);     //  2 MB
    float*  Opart = (float*)(ws);              // 16 MB  [1024 tiles][64][64]
    float*  lpart = (float*)(ws + 17*MB);      // 256 KB
    ushort* Qb    = (ushort*)(ws + 18*MB);     //  8 MB  [b,h,s,64] (Q scaled)
    ushort* Kb    = (ushort*)(ws + 26*MB);     //  8 MB  (== Qb + 4194304)
    ushort* VT    = (ushort*)(ws + 34*MB);     //  8 MB  [h*64+dv, b*2048+s]
    ushort* attnb = (ushort*)(ws + 42*MB);     //  8 MB  [4096,1024]
    float2* ropeT = (float2*)(ws + 50*MB);     //  0.5 MB
    ushort* Wob   = (ushort*)(ws + 51*MB);     //  2 MB  (survives to out-GEMM)

    dim3 blk(256);
    castall<<<4096, blk, 0, stream>>>(x, Wq, Wk, Wv, Wo, xb, Wqkb, Wvb, Wob);
    ropek<<<SEQ*32/256, blk, 0, stream>>>(pos, ropeT);

    proj_fused<<<1536, blk, 0, stream>>>(xb, Wqkb, Wvb, Qb, VT, ropeT);

    attn_mfma<<<dim3(48, NUM_HEADS, BATCHN), blk, 0, stream>>>(Qb, Kb, VT, attnb,
                                                               Opart, lpart);
    combine<<<512, blk, 0, stream>>>(Opart, lpart, attnb);

    gemm_out<<<dim3(16,32), blk, 0, stream>>>(attnb, Wob, out);
}

// Round 7
// 230.851 us; speedup vs baseline: 1.2450x; 1.2450x over previous
//
#include <hip/hip_runtime.h>
#include <hip/hip_bf16.h>
#include <math.h>

// Problem: B=2, S=2048, D=1024, H=16, dk=64. fp32 in/out, bf16 MFMA compute.
#define NUM_HEADS 16
#define DK 64
#define SEQ 2048
#define BATCHN 2
#define DM 1024
#define BS (BATCHN*SEQ)          // 4096
#define LSCALE 0.18033688011112042f   // 0.125 * log2(e), folded into Q

typedef __bf16 bf16x8 __attribute__((ext_vector_type(8)));
typedef float floatx4 __attribute__((ext_vector_type(4)));
typedef unsigned short ushort;
typedef unsigned int uint;

__device__ __forceinline__ ushort f2bu(float f){
    union { __hip_bfloat16 h; ushort u; } cv; cv.h = __float2bfloat16(f); return cv.u;
}
__device__ __forceinline__ uint packbf(float a, float b){
    return (uint)f2bu(a) | ((uint)f2bu(b) << 16);
}

// ---------------------------------------------------------------------------
// Fused fp32->bf16 casts: x (2048 blocks), Wq,Wk (into Wqk concat), Wv, Wo.
// ---------------------------------------------------------------------------
__global__ __launch_bounds__(256)
void castall(const float* __restrict__ x,  const float* __restrict__ wq,
             const float* __restrict__ wk, const float* __restrict__ wv,
             const float* __restrict__ wo, ushort* __restrict__ xb,
             ushort* __restrict__ wqkb, ushort* __restrict__ wvb,
             ushort* __restrict__ wob)
{
    int bid = blockIdx.x;
    const float* src; ushort* dst; int off;
    if (bid < 2048)      { src = x;  dst = xb;             off = bid; }
    else if (bid < 2560) { src = wq; dst = wqkb;           off = bid - 2048; }
    else if (bid < 3072) { src = wk; dst = wqkb + 1048576; off = bid - 2560; }
    else if (bid < 3584) { src = wv; dst = wvb;            off = bid - 3072; }
    else                 { src = wo; dst = wob;            off = bid - 3584; }
    int i = off*2048 + threadIdx.x*8;
    float4 a = *(const float4*)(src+i);
    float4 b = *(const float4*)(src+i+4);
    uint4 o;
    o.x = packbf(a.x, a.y);
    o.y = packbf(a.z, a.w);
    o.z = packbf(b.x, b.y);
    o.w = packbf(b.z, b.w);
    *(uint4*)(dst+i) = o;
}

// RoPE table: tab[s*32+i] = (cos, sin) of pos[s] * 10000^(-i/32)
__global__ __launch_bounds__(256) void ropek(const int* __restrict__ pos,
                                             float2* __restrict__ tab){
    int idx = blockIdx.x*256 + threadIdx.x;
    if (idx >= SEQ*32) return;
    int s = idx >> 5, i = idx & 31;
    float invf = expf(-0.28782313662425575f * (float)i);  // ln(1e4)/32
    float ang = (float)pos[s] * invf;
    float sn, cs; sincosf(ang, &sn, &cs);
    tab[idx] = make_float2(cs, sn);
}

// ---------------------------------------------------------------------------
// Fused projections, 128x128 tiles (768 blocks):
//   blocks 0..511  : QK proj, C = x·[Wq;Wk]^T, RoPE, scatter [b,h,s,64];
//                    Q scaled by LSCALE (folded softmax scale).
//   blocks 512..767: V^T proj, C = Wv·x^T row-major [1024, 4096].
// BK=32, 4 waves; each wave 32 rows x 128 cols.
// ---------------------------------------------------------------------------
__global__ __launch_bounds__(256)
void proj_fused(const ushort* __restrict__ xb, const ushort* __restrict__ Wqkb,
                const ushort* __restrict__ Wvb, ushort* __restrict__ Qb,
                ushort* __restrict__ VTp, const float2* __restrict__ rope)
{
    __shared__ ushort As[128][40];
    __shared__ ushort Bs[128][40];

    const int bid = blockIdx.x;
    const ushort* A; const ushort* W; int row0, col0, mode;
    if (bid < 512) { A = xb;  W = Wqkb; row0 = (bid >> 4) * 128;
                     col0 = (bid & 15) * 128;  mode = 1; }
    else           { int i = bid - 512; A = Wvb; W = xb;
                     row0 = (i >> 5) * 128; col0 = (i & 31) * 128; mode = 2; }

    const int t = threadIdx.x;
    const int w = t >> 6;
    const int L = t & 63;
    const int lr = L & 15;
    const int lq = L >> 4;
    const int wrow = w * 32;

    floatx4 acc[2][8];
    #pragma unroll
    for (int i = 0; i < 2; ++i)
        #pragma unroll
        for (int j = 0; j < 8; ++j)
            acc[i][j] = (floatx4){0.f,0.f,0.f,0.f};

    const int rr = t >> 2, ko = (t & 3) * 8;

    for (int k0 = 0; k0 < DM; k0 += 32) {
        const ushort* ap = A + (size_t)(row0 + rr) * DM + k0 + ko;
        uint4 va  = *(const uint4*)ap;
        uint4 va2 = *(const uint4*)(ap + (size_t)64 * DM);
        const ushort* wp = W + (size_t)(col0 + rr) * DM + k0 + ko;
        uint4 vb  = *(const uint4*)wp;
        uint4 vb2 = *(const uint4*)(wp + (size_t)64 * DM);
        *(uint4*)&As[rr][ko]      = va;
        *(uint4*)&As[rr + 64][ko] = va2;
        *(uint4*)&Bs[rr][ko]      = vb;
        *(uint4*)&Bs[rr + 64][ko] = vb2;
        __syncthreads();

        bf16x8 aF0 = *(const bf16x8*)&As[wrow + lr][lq*8];
        bf16x8 aF1 = *(const bf16x8*)&As[wrow + 16 + lr][lq*8];
        #pragma unroll
        for (int tc = 0; tc < 8; ++tc) {
            bf16x8 bF = *(const bf16x8*)&Bs[tc*16 + lr][lq*8];
            acc[0][tc] = __builtin_amdgcn_mfma_f32_16x16x32_bf16(aF0, bF, acc[0][tc], 0, 0, 0);
            acc[1][tc] = __builtin_amdgcn_mfma_f32_16x16x32_bf16(aF1, bF, acc[1][tc], 0, 0, 0);
        }
        __syncthreads();
    }

    // C layout: col = col0 + tc*16 + lr, row = row0+wrow+tr*16+lq*4+r
    if (mode == 2) {
        #pragma unroll
        for (int tr = 0; tr < 2; ++tr)
            #pragma unroll
            for (int tc = 0; tc < 8; ++tc)
                #pragma unroll
                for (int r = 0; r < 4; ++r) {
                    int m = row0 + wrow + tr*16 + lq*4 + r;
                    int c = col0 + tc*16 + lr;
                    VTp[(size_t)m * BS + c] = f2bu(acc[tr][tc][r]);
                }
    } else {
        const int mat = col0 >> 10;             // 0 = Q, 1 = K (tile never straddles)
        const int base_hh = (col0 & 1023) >> 6;
        ushort* out = Qb + (size_t)mat * (BATCHN*NUM_HEADS*SEQ*DK);
        const float qscale = mat ? 1.f : LSCALE;
        #pragma unroll
        for (int tr = 0; tr < 2; ++tr)
            #pragma unroll
            for (int tc = 0; tc < 8; ++tc)
                #pragma unroll
                for (int r = 0; r < 4; ++r) {
                    int m = row0 + wrow + tr*16 + lq*4 + r;
                    int b = m >> 11;
                    int s = m & (SEQ - 1);
                    int dd = (tc*16 + lr) & 63;
                    int hh = base_hh + (tc >> 2);
                    float v = acc[tr][tc][r];
                    float o = __shfl_xor(v, 1, 64);
                    float2 cs = rope[s*32 + (dd >> 1)];
                    float rv = (dd & 1) ? fmaf(o, cs.y,  v * cs.x)
                                        : fmaf(-o, cs.y, v * cs.x);
                    out[((size_t)((b*NUM_HEADS + hh)*SEQ + s))*DK + dd] =
                        f2bu(rv * qscale);
                }
    }
}

// ---------------------------------------------------------------------------
// Out projection, 128x128 tiles: out[m,n] = sum_k attnb[m,k]*Wo[n,k], fp32.
// grid (8, 32).
// ---------------------------------------------------------------------------
__global__ __launch_bounds__(256)
void gemm_out(const ushort* __restrict__ A, const ushort* __restrict__ W,
              float* __restrict__ out)
{
    __shared__ ushort As[128][40];
    __shared__ ushort Bs[128][40];

    const int t = threadIdx.x;
    const int w = t >> 6;
    const int L = t & 63;
    const int lr = L & 15;
    const int lq = L >> 4;
    const int row0 = blockIdx.y * 128;
    const int col0 = blockIdx.x * 128;
    const int wrow = w * 32;

    floatx4 acc[2][8];
    #pragma unroll
    for (int i = 0; i < 2; ++i)
        #pragma unroll
        for (int j = 0; j < 8; ++j)
            acc[i][j] = (floatx4){0.f,0.f,0.f,0.f};

    const int rr = t >> 2, ko = (t & 3) * 8;

    for (int k0 = 0; k0 < DM; k0 += 32) {
        const ushort* ap = A + (size_t)(row0 + rr) * DM + k0 + ko;
        uint4 va  = *(const uint4*)ap;
        uint4 va2 = *(const uint4*)(ap + (size_t)64 * DM);
        const ushort* wp = W + (size_t)(col0 + rr) * DM + k0 + ko;
        uint4 vb  = *(const uint4*)wp;
        uint4 vb2 = *(const uint4*)(wp + (size_t)64 * DM);
        *(uint4*)&As[rr][ko]      = va;
        *(uint4*)&As[rr + 64][ko] = va2;
        *(uint4*)&Bs[rr][ko]      = vb;
        *(uint4*)&Bs[rr + 64][ko] = vb2;
        __syncthreads();

        bf16x8 aF0 = *(const bf16x8*)&As[wrow + lr][lq*8];
        bf16x8 aF1 = *(const bf16x8*)&As[wrow + 16 + lr][lq*8];
        #pragma unroll
        for (int tc = 0; tc < 8; ++tc) {
            bf16x8 bF = *(const bf16x8*)&Bs[tc*16 + lr][lq*8];
            acc[0][tc] = __builtin_amdgcn_mfma_f32_16x16x32_bf16(aF0, bF, acc[0][tc], 0, 0, 0);
            acc[1][tc] = __builtin_amdgcn_mfma_f32_16x16x32_bf16(aF1, bF, acc[1][tc], 0, 0, 0);
        }
        __syncthreads();
    }

    #pragma unroll
    for (int tr = 0; tr < 2; ++tr)
        #pragma unroll
        for (int tc = 0; tc < 8; ++tc)
            #pragma unroll
            for (int r = 0; r < 4; ++r) {
                int m = row0 + wrow + tr*16 + lq*4 + r;
                int c = col0 + tc*16 + lr;
                out[(size_t)m * DM + c] = acc[tr][tc][r];
            }
}

// ---------------------------------------------------------------------------
// Flash attention, bf16 MFMA, no-max softmax, transposed QK (S^T = K·Q^T):
// lane's 4 accum regs = 4 consecutive keys for one q -> in-lane bf16 pair
// packing, ds_write_b64, no per-element shuffles. NO register prefetch (r6:
// compiler spilled it to scratch -> 272 MB/dispatch HBM writes). Q pre-scaled
// by LSCALE. Block: 4 waves x 16 q. grid.x=48 per (h,b): qt<16 -> 1 block;
// qt>=16 -> 2 key-range chunks (combined linearly by combine()).
// ---------------------------------------------------------------------------
__global__ __launch_bounds__(256)
void attn_mfma(const ushort* __restrict__ Qb, const ushort* __restrict__ Kb,
               const ushort* __restrict__ VT, ushort* __restrict__ attnb,
               float* __restrict__ Opart, float* __restrict__ lpart)
{
    __shared__ ushort Ks[128][72];     // [key][dim]
    __shared__ ushort Vs[64][136];     // [dim][key]
    __shared__ ushort Ps[4][16][136];  // per-wave P[q][key]

    const int t = threadIdx.x;
    const int w = t >> 6;
    const int L = t & 63;
    const int lr = L & 15, lq = L >> 4;
    const int h  = blockIdx.y;
    const int b  = blockIdx.z;

    int qt, t0, t1, chunk = 0; bool split;
    {
        const int bx = blockIdx.x;   // 0..47
        if (bx < 16) { qt = bx; t0 = 0; t1 = (qt >> 1) + 1; split = false; }
        else {
            int c2 = bx - 16; qt = 16 + (c2 >> 1); chunk = c2 & 1;
            int nt = (qt >> 1) + 1, half = nt >> 1;
            t0 = chunk ? half : 0; t1 = chunk ? nt : half; split = true;
        }
    }
    const int ntfull = (qt >> 1) + 1;
    const int q0 = qt * 64;
    const int qw = q0 + w * 16;
    const int qmax = q0 + 63;
    const size_t qkbase = (size_t)(b*NUM_HEADS + h) * SEQ * DK;

    bf16x8 qF0, qF1;
    {
        const ushort* qp = Qb + qkbase + (size_t)(qw + lr) * DK + lq*8;
        qF0 = *(const bf16x8*)qp;
        qF1 = *(const bf16x8*)(qp + 32);
    }

    floatx4 O[4];
    #pragma unroll
    for (int g = 0; g < 4; ++g) O[g] = (floatx4){0.f,0.f,0.f,0.f};
    float l_lane = 0.f;

    const int kr = t >> 3, kc8 = (t & 7) * 8;
    const int vr = t >> 4, vc8 = (t & 15) * 8;
    const ushort* kp0 = Kb + qkbase + (size_t)kr * DK + kc8;
    const ushort* vp0 = VT + ((size_t)(h*DK + vr)) * BS + b*SEQ + vc8;

    for (int tile = t0; tile < t1; ++tile) {
        const int kb = tile * 128;
        __syncthreads();
        {   // stage 128x64 K and 64x128 V^T directly (no register prefetch)
            #pragma unroll
            for (int c = 0; c < 4; ++c) {
                uint4 kv = *(const uint4*)(kp0 + (size_t)(kb + 32*c) * DK);
                uint4 vv = *(const uint4*)(vp0 + (size_t)(16*c) * BS + kb);
                *(uint4*)&Ks[32*c + kr][kc8] = kv;
                *(uint4*)&Vs[16*c + vr][vc8] = vv;
            }
        }
        __syncthreads();

        const int nc = min(4, ((qmax - kb) >> 5) + 1);  // active 32-key chunks
        const int ng = nc * 2;
        const bool lastt = (tile == ntfull - 1);
        const int lim = qw + lr - kb;                   // key offset <= lim ok

        #pragma unroll
        for (int g = 0; g < 8; ++g)
            if (g < ng) {
                floatx4 s = (floatx4){0.f,0.f,0.f,0.f};
                bf16x8 kf0 = *(const bf16x8*)&Ks[g*16 + lr][lq*8];
                bf16x8 kf1 = *(const bf16x8*)&Ks[g*16 + lr][32 + lq*8];
                // S^T = K·Q^T: lane -> q = qw+lr (col), key = kb+g*16+lq*4+r (row)
                s = __builtin_amdgcn_mfma_f32_16x16x32_bf16(kf0, qF0, s, 0, 0, 0);
                s = __builtin_amdgcn_mfma_f32_16x16x32_bf16(kf1, qF1, s, 0, 0, 0);
                float p0, p1, p2, p3;
                if (lastt) {
                    const int kbase = g*16 + lq*4;
                    p0 = (kbase + 0 <= lim) ? exp2f(s[0]) : 0.f;
                    p1 = (kbase + 1 <= lim) ? exp2f(s[1]) : 0.f;
                    p2 = (kbase + 2 <= lim) ? exp2f(s[2]) : 0.f;
                    p3 = (kbase + 3 <= lim) ? exp2f(s[3]) : 0.f;
                } else {
                    p0 = exp2f(s[0]); p1 = exp2f(s[1]);
                    p2 = exp2f(s[2]); p3 = exp2f(s[3]);
                }
                l_lane += (p0 + p1) + (p2 + p3);
                uint2 pk;
                pk.x = packbf(p0, p1);
                pk.y = packbf(p2, p3);
                *(uint2*)&Ps[w][lr][g*16 + lq*4] = pk;
            }
        asm volatile("s_waitcnt lgkmcnt(0)" ::: "memory");

        #pragma unroll
        for (int c = 0; c < 4; ++c)
            if (c < nc) {
                bf16x8 pF = *(const bf16x8*)&Ps[w][lr][c*32 + lq*8];
                #pragma unroll
                for (int g2 = 0; g2 < 4; ++g2) {
                    bf16x8 vf = *(const bf16x8*)&Vs[g2*16 + lr][c*32 + lq*8];
                    O[g2] = __builtin_amdgcn_mfma_f32_16x16x32_bf16(pF, vf, O[g2], 0, 0, 0);
                }
            }
    }

    // l for q=qw+lr: sum across the 4 lq lanes sharing lr
    l_lane += __shfl_xor(l_lane, 16, 64);
    l_lane += __shfl_xor(l_lane, 32, 64);

    if (!split) {
        #pragma unroll
        for (int r = 0; r < 4; ++r) {
            float lv = __shfl(l_lane, lq*4 + r, 64);   // l for q row lq*4+r
            float li = 1.f / lv;
            int s = qw + lq*4 + r;
            #pragma unroll
            for (int g2 = 0; g2 < 4; ++g2)
                attnb[((size_t)(b*SEQ + s))*DM + h*DK + g2*16 + lr] = f2bu(O[g2][r] * li);
        }
    } else {
        const size_t tb = (size_t)((b*NUM_HEADS + h)*16 + (qt - 16)) * 2 + chunk;
        float* Op = Opart + tb * 4096;
        #pragma unroll
        for (int r = 0; r < 4; ++r) {
            int ql = w*16 + lq*4 + r;
            #pragma unroll
            for (int g2 = 0; g2 < 4; ++g2)
                Op[ql*64 + g2*16 + lr] = O[g2][r];
        }
        if (lq == 0) lpart[tb*64 + w*16 + lr] = l_lane;
    }
}

// ---------------------------------------------------------------------------
// Combine: for qt>=16, O = (O0+O1)/(l0+l1) -> attnb bf16. 512 blocks.
// ---------------------------------------------------------------------------
__global__ __launch_bounds__(256)
void combine(const float* __restrict__ Opart, const float* __restrict__ lpart,
             ushort* __restrict__ attnb)
{
    int gx = blockIdx.x;            // 512 = 32 (b,h) x 16 qt
    int qti = gx & 15, bh = gx >> 4;
    int h = bh & 15, b = bh >> 4;
    int qt = 16 + qti;
    int tid = threadIdx.x;
    int row = tid >> 2, c0 = (tid & 3) * 16;
    size_t tb = (size_t)(bh*16 + qti) * 2;
    const float* O0 = Opart + tb*4096 + row*64 + c0;
    const float* O1 = O0 + 4096;
    float l = lpart[tb*64 + row] + lpart[tb*64 + 64 + row];
    float li = 1.f / l;
    int s = qt*64 + row;
    ushort* dst = attnb + ((size_t)(b*SEQ + s))*DM + h*DK + c0;
    #pragma unroll
    for (int e = 0; e < 16; e += 4) {
        float4 a = *(const float4*)(O0 + e);
        float4 c = *(const float4*)(O1 + e);
        dst[e+0] = f2bu((a.x + c.x) * li);
        dst[e+1] = f2bu((a.y + c.y) * li);
        dst[e+2] = f2bu((a.z + c.z) * li);
        dst[e+3] = f2bu((a.w + c.w) * li);
    }
}

// ---------------------------------------------------------------------------
extern "C" void kernel_launch(void* const* d_in, const int* in_sizes, int n_in,
                              void* d_out, int out_size, void* d_ws, size_t ws_size,
                              hipStream_t stream) {
    const float* x   = (const float*)d_in[0];
    const float* Wq  = (const float*)d_in[1];
    const float* Wk  = (const float*)d_in[2];
    const float* Wv  = (const float*)d_in[3];
    const float* Wo  = (const float*)d_in[4];
    const int*   pos = (const int*)d_in[5];
    float* out = (float*)d_out;

    const size_t MB = 1u << 20;
    char* ws = (char*)d_ws;
    // xb/Wqkb/Wvb dead after projections; Opart (16 MB) aliases them.
    ushort* xb    = (ushort*)(ws);             //  8 MB  [4096,1024]
    ushort* Wqkb  = (ushort*)(ws +  8*MB);     //  4 MB  [Wq;Wk]
    ushort* Wvb   = (ushort*)(ws + 12*MB);     //  2 MB
    float*  Opart = (float*)(ws);              // 16 MB  [1024 tiles][64][64]
    float*  lpart = (float*)(ws + 17*MB);      // 256 KB
    ushort* Qb    = (ushort*)(ws + 18*MB);     //  8 MB  [b,h,s,64] (Q scaled)
    ushort* Kb    = (ushort*)(ws + 26*MB);     //  8 MB  (== Qb + 4194304)
    ushort* VT    = (ushort*)(ws + 34*MB);     //  8 MB  [h*64+dv, b*2048+s]
    ushort* attnb = (ushort*)(ws + 42*MB);     //  8 MB  [4096,1024]
    float2* ropeT = (float2*)(ws + 50*MB);     //  0.5 MB
    ushort* Wob   = (ushort*)(ws + 51*MB);     //  2 MB  (survives to out-GEMM)

    dim3 blk(256);
    castall<<<4096, blk, 0, stream>>>(x, Wq, Wk, Wv, Wo, xb, Wqkb, Wvb, Wob);
    ropek<<<SEQ*32/256, blk, 0, stream>>>(pos, ropeT);

    proj_fused<<<768, blk, 0, stream>>>(xb, Wqkb, Wvb, Qb, VT, ropeT);

    attn_mfma<<<dim3(48, NUM_HEADS, BATCHN), blk, 0, stream>>>(Qb, Kb, VT, attnb,
                                                               Opart, lpart);
    combine<<<512, blk, 0, stream>>>(Opart, lpart, attnb);

    gemm_out<<<dim3(8,32), blk, 0, stream>>>(attnb, Wob, out);
}

// Round 8
// 224.042 us; speedup vs baseline: 1.2829x; 1.0304x over previous
//
#include <hip/hip_runtime.h>
#include <hip/hip_bf16.h>
#include <math.h>

// Problem: B=2, S=2048, D=1024, H=16, dk=64. fp32 in/out, bf16 MFMA compute.
#define NUM_HEADS 16
#define DK 64
#define SEQ 2048
#define BATCHN 2
#define DM 1024
#define BS (BATCHN*SEQ)          // 4096
#define LSCALE 0.18033688011112042f   // 0.125 * log2(e), folded into Q

typedef __bf16 bf16x8 __attribute__((ext_vector_type(8)));
typedef float floatx4 __attribute__((ext_vector_type(4)));
typedef unsigned short ushort;
typedef unsigned int uint;

__device__ __forceinline__ ushort f2bu(float f){
    union { __hip_bfloat16 h; ushort u; } cv; cv.h = __float2bfloat16(f); return cv.u;
}
__device__ __forceinline__ uint packbf(float a, float b){
    return (uint)f2bu(a) | ((uint)f2bu(b) << 16);
}

// ---------------------------------------------------------------------------
// Fused fp32->bf16 casts + RoPE table (one launch, 4352 blocks):
//   0..2047 x, 2048..3071 Wq|Wk, 3072..3583 Wv, 3584..4095 Wo,
//   4096..4351 rope table: tab[s*32+i] = (cos,sin) pos[s]*10000^(-i/32).
// ---------------------------------------------------------------------------
__global__ __launch_bounds__(256)
void castall(const float* __restrict__ x,  const float* __restrict__ wq,
             const float* __restrict__ wk, const float* __restrict__ wv,
             const float* __restrict__ wo, const int* __restrict__ pos,
             ushort* __restrict__ xb, ushort* __restrict__ wqkb,
             ushort* __restrict__ wvb, ushort* __restrict__ wob,
             float2* __restrict__ tab)
{
    int bid = blockIdx.x;
    if (bid >= 4096) {
        int idx = (bid - 4096)*256 + threadIdx.x;   // 0..65535
        int s = idx >> 5, i = idx & 31;
        float invf = expf(-0.28782313662425575f * (float)i);  // ln(1e4)/32
        float ang = (float)pos[s] * invf;
        float sn, cs; sincosf(ang, &sn, &cs);
        tab[idx] = make_float2(cs, sn);
        return;
    }
    const float* src; ushort* dst; int off;
    if (bid < 2048)      { src = x;  dst = xb;             off = bid; }
    else if (bid < 2560) { src = wq; dst = wqkb;           off = bid - 2048; }
    else if (bid < 3072) { src = wk; dst = wqkb + 1048576; off = bid - 2560; }
    else if (bid < 3584) { src = wv; dst = wvb;            off = bid - 3072; }
    else                 { src = wo; dst = wob;            off = bid - 3584; }
    int i = off*2048 + threadIdx.x*8;
    float4 a = *(const float4*)(src+i);
    float4 b = *(const float4*)(src+i+4);
    uint4 o;
    o.x = packbf(a.x, a.y);
    o.y = packbf(a.z, a.w);
    o.z = packbf(b.x, b.y);
    o.w = packbf(b.z, b.w);
    *(uint4*)(dst+i) = o;
}

// ---------------------------------------------------------------------------
// Fused projections, 128x128 tiles (768 blocks):
//   blocks 0..511  : QK proj, C = x·[Wq;Wk]^T, RoPE, scatter [b,h,s,64];
//                    Q scaled by LSCALE (folded softmax scale).
//   blocks 512..767: V^T proj, C = Wv·x^T row-major [1024, 4096].
// BK=32, 4 waves; each wave 32 rows x 128 cols.
// ---------------------------------------------------------------------------
__global__ __launch_bounds__(256)
void proj_fused(const ushort* __restrict__ xb, const ushort* __restrict__ Wqkb,
                const ushort* __restrict__ Wvb, ushort* __restrict__ Qb,
                ushort* __restrict__ VTp, const float2* __restrict__ rope)
{
    __shared__ ushort As[128][40];
    __shared__ ushort Bs[128][40];

    const int bid = blockIdx.x;
    const ushort* A; const ushort* W; int row0, col0, mode;
    if (bid < 512) { A = xb;  W = Wqkb; row0 = (bid >> 4) * 128;
                     col0 = (bid & 15) * 128;  mode = 1; }
    else           { int i = bid - 512; A = Wvb; W = xb;
                     row0 = (i >> 5) * 128; col0 = (i & 31) * 128; mode = 2; }

    const int t = threadIdx.x;
    const int w = t >> 6;
    const int L = t & 63;
    const int lr = L & 15;
    const int lq = L >> 4;
    const int wrow = w * 32;

    floatx4 acc[2][8];
    #pragma unroll
    for (int i = 0; i < 2; ++i)
        #pragma unroll
        for (int j = 0; j < 8; ++j)
            acc[i][j] = (floatx4){0.f,0.f,0.f,0.f};

    const int rr = t >> 2, ko = (t & 3) * 8;

    for (int k0 = 0; k0 < DM; k0 += 32) {
        const ushort* ap = A + (size_t)(row0 + rr) * DM + k0 + ko;
        uint4 va  = *(const uint4*)ap;
        uint4 va2 = *(const uint4*)(ap + (size_t)64 * DM);
        const ushort* wp = W + (size_t)(col0 + rr) * DM + k0 + ko;
        uint4 vb  = *(const uint4*)wp;
        uint4 vb2 = *(const uint4*)(wp + (size_t)64 * DM);
        *(uint4*)&As[rr][ko]      = va;
        *(uint4*)&As[rr + 64][ko] = va2;
        *(uint4*)&Bs[rr][ko]      = vb;
        *(uint4*)&Bs[rr + 64][ko] = vb2;
        __syncthreads();

        bf16x8 aF0 = *(const bf16x8*)&As[wrow + lr][lq*8];
        bf16x8 aF1 = *(const bf16x8*)&As[wrow + 16 + lr][lq*8];
        #pragma unroll
        for (int tc = 0; tc < 8; ++tc) {
            bf16x8 bF = *(const bf16x8*)&Bs[tc*16 + lr][lq*8];
            acc[0][tc] = __builtin_amdgcn_mfma_f32_16x16x32_bf16(aF0, bF, acc[0][tc], 0, 0, 0);
            acc[1][tc] = __builtin_amdgcn_mfma_f32_16x16x32_bf16(aF1, bF, acc[1][tc], 0, 0, 0);
        }
        __syncthreads();
    }

    // C layout: col = col0 + tc*16 + lr, row = row0+wrow+tr*16+lq*4+r
    if (mode == 2) {
        #pragma unroll
        for (int tr = 0; tr < 2; ++tr)
            #pragma unroll
            for (int tc = 0; tc < 8; ++tc)
                #pragma unroll
                for (int r = 0; r < 4; ++r) {
                    int m = row0 + wrow + tr*16 + lq*4 + r;
                    int c = col0 + tc*16 + lr;
                    VTp[(size_t)m * BS + c] = f2bu(acc[tr][tc][r]);
                }
    } else {
        const int mat = col0 >> 10;             // 0 = Q, 1 = K (tile never straddles)
        const int base_hh = (col0 & 1023) >> 6;
        ushort* out = Qb + (size_t)mat * (BATCHN*NUM_HEADS*SEQ*DK);
        const float qscale = mat ? 1.f : LSCALE;
        #pragma unroll
        for (int tr = 0; tr < 2; ++tr)
            #pragma unroll
            for (int tc = 0; tc < 8; ++tc)
                #pragma unroll
                for (int r = 0; r < 4; ++r) {
                    int m = row0 + wrow + tr*16 + lq*4 + r;
                    int b = m >> 11;
                    int s = m & (SEQ - 1);
                    int dd = (tc*16 + lr) & 63;
                    int hh = base_hh + (tc >> 2);
                    float v = acc[tr][tc][r];
                    float o = __shfl_xor(v, 1, 64);
                    float2 cs = rope[s*32 + (dd >> 1)];
                    float rv = (dd & 1) ? fmaf(o, cs.y,  v * cs.x)
                                        : fmaf(-o, cs.y, v * cs.x);
                    out[((size_t)((b*NUM_HEADS + hh)*SEQ + s))*DK + dd] =
                        f2bu(rv * qscale);
                }
    }
}

// ---------------------------------------------------------------------------
// Out projection, 128x128 tiles: out[m,n] = sum_k attnb[m,k]*Wo[n,k], fp32.
// grid (8, 32).
// ---------------------------------------------------------------------------
__global__ __launch_bounds__(256)
void gemm_out(const ushort* __restrict__ A, const ushort* __restrict__ W,
              float* __restrict__ out)
{
    __shared__ ushort As[128][40];
    __shared__ ushort Bs[128][40];

    const int t = threadIdx.x;
    const int w = t >> 6;
    const int L = t & 63;
    const int lr = L & 15;
    const int lq = L >> 4;
    const int row0 = blockIdx.y * 128;
    const int col0 = blockIdx.x * 128;
    const int wrow = w * 32;

    floatx4 acc[2][8];
    #pragma unroll
    for (int i = 0; i < 2; ++i)
        #pragma unroll
        for (int j = 0; j < 8; ++j)
            acc[i][j] = (floatx4){0.f,0.f,0.f,0.f};

    const int rr = t >> 2, ko = (t & 3) * 8;

    for (int k0 = 0; k0 < DM; k0 += 32) {
        const ushort* ap = A + (size_t)(row0 + rr) * DM + k0 + ko;
        uint4 va  = *(const uint4*)ap;
        uint4 va2 = *(const uint4*)(ap + (size_t)64 * DM);
        const ushort* wp = W + (size_t)(col0 + rr) * DM + k0 + ko;
        uint4 vb  = *(const uint4*)wp;
        uint4 vb2 = *(const uint4*)(wp + (size_t)64 * DM);
        *(uint4*)&As[rr][ko]      = va;
        *(uint4*)&As[rr + 64][ko] = va2;
        *(uint4*)&Bs[rr][ko]      = vb;
        *(uint4*)&Bs[rr + 64][ko] = vb2;
        __syncthreads();

        bf16x8 aF0 = *(const bf16x8*)&As[wrow + lr][lq*8];
        bf16x8 aF1 = *(const bf16x8*)&As[wrow + 16 + lr][lq*8];
        #pragma unroll
        for (int tc = 0; tc < 8; ++tc) {
            bf16x8 bF = *(const bf16x8*)&Bs[tc*16 + lr][lq*8];
            acc[0][tc] = __builtin_amdgcn_mfma_f32_16x16x32_bf16(aF0, bF, acc[0][tc], 0, 0, 0);
            acc[1][tc] = __builtin_amdgcn_mfma_f32_16x16x32_bf16(aF1, bF, acc[1][tc], 0, 0, 0);
        }
        __syncthreads();
    }

    #pragma unroll
    for (int tr = 0; tr < 2; ++tr)
        #pragma unroll
        for (int tc = 0; tc < 8; ++tc)
            #pragma unroll
            for (int r = 0; r < 4; ++r) {
                int m = row0 + wrow + tr*16 + lq*4 + r;
                int c = col0 + tc*16 + lr;
                out[(size_t)m * DM + c] = acc[tr][tc][r];
            }
}

// ---------------------------------------------------------------------------
// Flash attention, bf16 MFMA, no-max softmax, transposed QK (S^T = K·Q^T).
// 64-key tiles: LDS 27.6 KB -> 5 blocks/CU (vs 3 at 128-key) for latency
// hiding; per-key work unchanged, masked-chunk machinery gone (all groups
// always active; mask only on the diagonal tile). Block: 4 waves x 16 q.
// grid.x=48 per (h,b): qt<16 -> 1 block (qt+1 tiles); qt>=16 -> 2 key-range
// chunks (combined linearly by combine()).
// ---------------------------------------------------------------------------
__global__ __launch_bounds__(256)
void attn_mfma(const ushort* __restrict__ Qb, const ushort* __restrict__ Kb,
               const ushort* __restrict__ VT, ushort* __restrict__ attnb,
               float* __restrict__ Opart, float* __restrict__ lpart)
{
    __shared__ ushort Ks[64][72];      // [key][dim]
    __shared__ ushort Vs[64][72];      // [dim][key]
    __shared__ ushort Ps[4][16][72];   // per-wave P[q][key]

    const int t = threadIdx.x;
    const int w = t >> 6;
    const int L = t & 63;
    const int lr = L & 15, lq = L >> 4;
    const int h  = blockIdx.y;
    const int b  = blockIdx.z;

    int qt, t0, t1, chunk = 0; bool split;
    {
        const int bx = blockIdx.x;   // 0..47
        if (bx < 16) { qt = bx; t0 = 0; t1 = qt + 1; split = false; }
        else {
            int c2 = bx - 16; qt = 16 + (c2 >> 1); chunk = c2 & 1;
            int nt = qt + 1, half = nt >> 1;
            t0 = chunk ? half : 0; t1 = chunk ? nt : half; split = true;
        }
    }
    const int ntfull = qt + 1;
    const int q0 = qt * 64;
    const int qw = q0 + w * 16;
    const size_t qkbase = (size_t)(b*NUM_HEADS + h) * SEQ * DK;

    bf16x8 qF0, qF1;
    {
        const ushort* qp = Qb + qkbase + (size_t)(qw + lr) * DK + lq*8;
        qF0 = *(const bf16x8*)qp;
        qF1 = *(const bf16x8*)(qp + 32);
    }

    floatx4 O[4];
    #pragma unroll
    for (int g = 0; g < 4; ++g) O[g] = (floatx4){0.f,0.f,0.f,0.f};
    float l_lane = 0.f;

    // staging: 64x64 K (8 KB) + 64x64 V^T (8 KB); 2 uint4 each per thread
    const int sr = t >> 3, sc = (t & 7) * 8;   // row 0..31 (+32), chunk 0..7
    const ushort* kp0 = Kb + qkbase + (size_t)sr * DK + sc;
    const ushort* vp0 = VT + ((size_t)(h*DK + sr)) * BS + b*SEQ + sc;

    for (int tile = t0; tile < t1; ++tile) {
        const int kb = tile * 64;
        __syncthreads();
        {
            uint4 k0v = *(const uint4*)(kp0 + (size_t)kb * DK);
            uint4 k1v = *(const uint4*)(kp0 + (size_t)(kb + 32) * DK);
            uint4 v0v = *(const uint4*)(vp0 + kb);
            uint4 v1v = *(const uint4*)(vp0 + (size_t)32 * BS + kb);
            *(uint4*)&Ks[sr][sc]      = k0v;
            *(uint4*)&Ks[sr + 32][sc] = k1v;
            *(uint4*)&Vs[sr][sc]      = v0v;
            *(uint4*)&Vs[sr + 32][sc] = v1v;
        }
        __syncthreads();

        const bool lastt = (tile == ntfull - 1);
        const int lim = qw + lr - kb;          // key offset <= lim is unmasked

        #pragma unroll
        for (int g = 0; g < 4; ++g) {
            floatx4 s = (floatx4){0.f,0.f,0.f,0.f};
            bf16x8 kf0 = *(const bf16x8*)&Ks[g*16 + lr][lq*8];
            bf16x8 kf1 = *(const bf16x8*)&Ks[g*16 + lr][32 + lq*8];
            // S^T = K·Q^T: lane -> q = qw+lr (col), key = kb+g*16+lq*4+r (row)
            s = __builtin_amdgcn_mfma_f32_16x16x32_bf16(kf0, qF0, s, 0, 0, 0);
            s = __builtin_amdgcn_mfma_f32_16x16x32_bf16(kf1, qF1, s, 0, 0, 0);
            float p0, p1, p2, p3;
            if (lastt) {
                const int kbase = g*16 + lq*4;
                p0 = (kbase + 0 <= lim) ? exp2f(s[0]) : 0.f;
                p1 = (kbase + 1 <= lim) ? exp2f(s[1]) : 0.f;
                p2 = (kbase + 2 <= lim) ? exp2f(s[2]) : 0.f;
                p3 = (kbase + 3 <= lim) ? exp2f(s[3]) : 0.f;
            } else {
                p0 = exp2f(s[0]); p1 = exp2f(s[1]);
                p2 = exp2f(s[2]); p3 = exp2f(s[3]);
            }
            l_lane += (p0 + p1) + (p2 + p3);
            uint2 pk;
            pk.x = packbf(p0, p1);
            pk.y = packbf(p2, p3);
            *(uint2*)&Ps[w][lr][g*16 + lq*4] = pk;
        }
        asm volatile("s_waitcnt lgkmcnt(0)" ::: "memory");

        #pragma unroll
        for (int c = 0; c < 2; ++c) {
            bf16x8 pF = *(const bf16x8*)&Ps[w][lr][c*32 + lq*8];
            #pragma unroll
            for (int g2 = 0; g2 < 4; ++g2) {
                bf16x8 vf = *(const bf16x8*)&Vs[g2*16 + lr][c*32 + lq*8];
                O[g2] = __builtin_amdgcn_mfma_f32_16x16x32_bf16(pF, vf, O[g2], 0, 0, 0);
            }
        }
    }

    // l for q=qw+lr: sum across the 4 lq lanes sharing lr
    l_lane += __shfl_xor(l_lane, 16, 64);
    l_lane += __shfl_xor(l_lane, 32, 64);

    if (!split) {
        #pragma unroll
        for (int r = 0; r < 4; ++r) {
            float lv = __shfl(l_lane, lq*4 + r, 64);   // l for q row lq*4+r
            float li = 1.f / lv;
            int s = qw + lq*4 + r;
            #pragma unroll
            for (int g2 = 0; g2 < 4; ++g2)
                attnb[((size_t)(b*SEQ + s))*DM + h*DK + g2*16 + lr] = f2bu(O[g2][r] * li);
        }
    } else {
        const size_t tb = (size_t)((b*NUM_HEADS + h)*16 + (qt - 16)) * 2 + chunk;
        float* Op = Opart + tb * 4096;
        #pragma unroll
        for (int r = 0; r < 4; ++r) {
            int ql = w*16 + lq*4 + r;
            #pragma unroll
            for (int g2 = 0; g2 < 4; ++g2)
                Op[ql*64 + g2*16 + lr] = O[g2][r];
        }
        if (lq == 0) lpart[tb*64 + w*16 + lr] = l_lane;
    }
}

// ---------------------------------------------------------------------------
// Combine: for qt>=16, O = (O0+O1)/(l0+l1) -> attnb bf16. 512 blocks.
// ---------------------------------------------------------------------------
__global__ __launch_bounds__(256)
void combine(const float* __restrict__ Opart, const float* __restrict__ lpart,
             ushort* __restrict__ attnb)
{
    int gx = blockIdx.x;            // 512 = 32 (b,h) x 16 qt
    int qti = gx & 15, bh = gx >> 4;
    int h = bh & 15, b = bh >> 4;
    int qt = 16 + qti;
    int tid = threadIdx.x;
    int row = tid >> 2, c0 = (tid & 3) * 16;
    size_t tb = (size_t)(bh*16 + qti) * 2;
    const float* O0 = Opart + tb*4096 + row*64 + c0;
    const float* O1 = O0 + 4096;
    float l = lpart[tb*64 + row] + lpart[tb*64 + 64 + row];
    float li = 1.f / l;
    int s = qt*64 + row;
    ushort* dst = attnb + ((size_t)(b*SEQ + s))*DM + h*DK + c0;
    #pragma unroll
    for (int e = 0; e < 16; e += 4) {
        float4 a = *(const float4*)(O0 + e);
        float4 c = *(const float4*)(O1 + e);
        dst[e+0] = f2bu((a.x + c.x) * li);
        dst[e+1] = f2bu((a.y + c.y) * li);
        dst[e+2] = f2bu((a.z + c.z) * li);
        dst[e+3] = f2bu((a.w + c.w) * li);
    }
}

// ---------------------------------------------------------------------------
extern "C" void kernel_launch(void* const* d_in, const int* in_sizes, int n_in,
                              void* d_out, int out_size, void* d_ws, size_t ws_size,
                              hipStream_t stream) {
    const float* x   = (const float*)d_in[0];
    const float* Wq  = (const float*)d_in[1];
    const float* Wk  = (const float*)d_in[2];
    const float* Wv  = (const float*)d_in[3];
    const float* Wo  = (const float*)d_in[4];
    const int*   pos = (const int*)d_in[5];
    float* out = (float*)d_out;

    const size_t MB = 1u << 20;
    char* ws = (char*)d_ws;
    // xb/Wqkb/Wvb dead after projections; Opart (16 MB) aliases them.
    ushort* xb    = (ushort*)(ws);             //  8 MB  [4096,1024]
    ushort* Wqkb  = (ushort*)(ws +  8*MB);     //  4 MB  [Wq;Wk]
    ushort* Wvb   = (ushort*)(ws + 12*MB);     //  2 MB
    float*  Opart = (float*)(ws);              // 16 MB  [1024 tiles][64][64]
    float*  lpart = (float*)(ws + 17*MB);      // 256 KB
    ushort* Qb    = (ushort*)(ws + 18*MB);     //  8 MB  [b,h,s,64] (Q scaled)
    ushort* Kb    = (ushort*)(ws + 26*MB);     //  8 MB  (== Qb + 4194304)
    ushort* VT    = (ushort*)(ws + 34*MB);     //  8 MB  [h*64+dv, b*2048+s]
    ushort* attnb = (ushort*)(ws + 42*MB);     //  8 MB  [4096,1024]
    float2* ropeT = (float2*)(ws + 50*MB);     //  0.5 MB
    ushort* Wob   = (ushort*)(ws + 51*MB);     //  2 MB  (survives to out-GEMM)

    dim3 blk(256);
    castall<<<4352, blk, 0, stream>>>(x, Wq, Wk, Wv, Wo, pos,
                                      xb, Wqkb, Wvb, Wob, ropeT);

    proj_fused<<<768, blk, 0, stream>>>(xb, Wqkb, Wvb, Qb, VT, ropeT);

    attn_mfma<<<dim3(48, NUM_HEADS, BATCHN), blk, 0, stream>>>(Qb, Kb, VT, attnb,
                                                               Opart, lpart);
    combine<<<512, blk, 0, stream>>>(Opart, lpart, attnb);

    gemm_out<<<dim3(8,32), blk, 0, stream>>>(attnb, Wob, out);
}

// Round 9
// 200.828 us; speedup vs baseline: 1.4312x; 1.1156x over previous
//
#include <hip/hip_runtime.h>
#include <hip/hip_bf16.h>
#include <math.h>

// Problem: B=2, S=2048, D=1024, H=16, dk=64. fp32 in/out, bf16 MFMA compute.
#define NUM_HEADS 16
#define DK 64
#define SEQ 2048
#define BATCHN 2
#define DM 1024
#define BS (BATCHN*SEQ)          // 4096
#define LSCALE 0.18033688011112042f   // 0.125 * log2(e), folded into Q

typedef __bf16 bf16x8 __attribute__((ext_vector_type(8)));
typedef float floatx4 __attribute__((ext_vector_type(4)));
typedef unsigned short ushort;
typedef unsigned int uint;

__device__ __forceinline__ ushort f2bu(float f){
    union { __hip_bfloat16 h; ushort u; } cv; cv.h = __float2bfloat16(f); return cv.u;
}
__device__ __forceinline__ uint packbf(float a, float b){
    return (uint)f2bu(a) | ((uint)f2bu(b) << 16);
}
__device__ __forceinline__ float bu2f(ushort u){
    union { uint u; float f; } cv; cv.u = (uint)u << 16; return cv.f;
}
// async global->LDS, 16 B per lane; LDS dst must be wave-uniform-base + lane*16
__device__ __forceinline__ void gl16(const void* g, void* l){
    __builtin_amdgcn_global_load_lds(
        (const __attribute__((address_space(1))) unsigned int*)g,
        (__attribute__((address_space(3))) unsigned int*)l, 16, 0, 0);
}

// ---------------------------------------------------------------------------
// Fused fp32->bf16 casts + RoPE table (one launch, 4352 blocks).
// ---------------------------------------------------------------------------
__global__ __launch_bounds__(256)
void castall(const float* __restrict__ x,  const float* __restrict__ wq,
             const float* __restrict__ wk, const float* __restrict__ wv,
             const float* __restrict__ wo, const int* __restrict__ pos,
             ushort* __restrict__ xb, ushort* __restrict__ wqkb,
             ushort* __restrict__ wvb, ushort* __restrict__ wob,
             float2* __restrict__ tab)
{
    int bid = blockIdx.x;
    if (bid >= 4096) {
        int idx = (bid - 4096)*256 + threadIdx.x;   // 0..65535
        int s = idx >> 5, i = idx & 31;
        float invf = expf(-0.28782313662425575f * (float)i);  // ln(1e4)/32
        float ang = (float)pos[s] * invf;
        float sn, cs; sincosf(ang, &sn, &cs);
        tab[idx] = make_float2(cs, sn);
        return;
    }
    const float* src; ushort* dst; int off;
    if (bid < 2048)      { src = x;  dst = xb;             off = bid; }
    else if (bid < 2560) { src = wq; dst = wqkb;           off = bid - 2048; }
    else if (bid < 3072) { src = wk; dst = wqkb + 1048576; off = bid - 2560; }
    else if (bid < 3584) { src = wv; dst = wvb;            off = bid - 3072; }
    else                 { src = wo; dst = wob;            off = bid - 3584; }
    int i = off*2048 + threadIdx.x*8;
    float4 a = *(const float4*)(src+i);
    float4 b = *(const float4*)(src+i+4);
    uint4 o;
    o.x = packbf(a.x, a.y);
    o.y = packbf(a.z, a.w);
    o.z = packbf(b.x, b.y);
    o.w = packbf(b.z, b.w);
    *(uint4*)(dst+i) = o;
}

// ---------------------------------------------------------------------------
// Fused projections, 128x128 tiles (768 blocks), m97-style global_load_lds
// staging (unpadded [.][32] LDS: lane-contiguous, bank-uniform).
//   blocks 0..511  : QK proj + RoPE scatter [b,h,s,64]; Q scaled by LSCALE.
//   blocks 512..767: V^T proj row-major [1024, 4096].
// ---------------------------------------------------------------------------
__global__ __launch_bounds__(256)
void proj_fused(const ushort* __restrict__ xb, const ushort* __restrict__ Wqkb,
                const ushort* __restrict__ Wvb, ushort* __restrict__ Qb,
                ushort* __restrict__ VTp, const float2* __restrict__ rope)
{
    __shared__ ushort As[128][32];
    __shared__ ushort Bs[128][32];

    const int bid = blockIdx.x;
    const ushort* A; const ushort* W; int row0, col0, mode;
    if (bid < 512) { A = xb;  W = Wqkb; row0 = (bid >> 4) * 128;
                     col0 = (bid & 15) * 128;  mode = 1; }
    else           { int i = bid - 512; A = Wvb; W = xb;
                     row0 = (i >> 5) * 128; col0 = (i & 31) * 128; mode = 2; }

    const int t = threadIdx.x;
    const int w = t >> 6;
    const int L = t & 63;
    const int lr = L & 15;
    const int lq = L >> 4;
    const int wrow = w * 32;

    floatx4 acc[2][8];
    #pragma unroll
    for (int i = 0; i < 2; ++i)
        #pragma unroll
        for (int j = 0; j < 8; ++j)
            acc[i][j] = (floatx4){0.f,0.f,0.f,0.f};

    const int rr = t >> 2, ko = (t & 3) * 8;   // LDS offset = t*16 B (lane-contig)
    const ushort* ga = A + (size_t)(row0 + rr) * DM + ko;
    const ushort* gb = W + (size_t)(col0 + rr) * DM + ko;

    for (int k0 = 0; k0 < DM; k0 += 32) {
        __syncthreads();
        gl16(ga + k0,                    &As[rr][ko]);
        gl16(ga + k0 + (size_t)64*DM,    &As[rr + 64][ko]);
        gl16(gb + k0,                    &Bs[rr][ko]);
        gl16(gb + k0 + (size_t)64*DM,    &Bs[rr + 64][ko]);
        __syncthreads();

        bf16x8 aF0 = *(const bf16x8*)&As[wrow + lr][lq*8];
        bf16x8 aF1 = *(const bf16x8*)&As[wrow + 16 + lr][lq*8];
        #pragma unroll
        for (int tc = 0; tc < 8; ++tc) {
            bf16x8 bF = *(const bf16x8*)&Bs[tc*16 + lr][lq*8];
            acc[0][tc] = __builtin_amdgcn_mfma_f32_16x16x32_bf16(aF0, bF, acc[0][tc], 0, 0, 0);
            acc[1][tc] = __builtin_amdgcn_mfma_f32_16x16x32_bf16(aF1, bF, acc[1][tc], 0, 0, 0);
        }
    }

    // C layout: col = col0 + tc*16 + lr, row = row0+wrow+tr*16+lq*4+r
    if (mode == 2) {
        #pragma unroll
        for (int tr = 0; tr < 2; ++tr)
            #pragma unroll
            for (int tc = 0; tc < 8; ++tc)
                #pragma unroll
                for (int r = 0; r < 4; ++r) {
                    int m = row0 + wrow + tr*16 + lq*4 + r;
                    int c = col0 + tc*16 + lr;
                    VTp[(size_t)m * BS + c] = f2bu(acc[tr][tc][r]);
                }
    } else {
        const int mat = col0 >> 10;             // 0 = Q, 1 = K (tile never straddles)
        const int base_hh = (col0 & 1023) >> 6;
        ushort* out = Qb + (size_t)mat * (BATCHN*NUM_HEADS*SEQ*DK);
        const float qscale = mat ? 1.f : LSCALE;
        #pragma unroll
        for (int tr = 0; tr < 2; ++tr)
            #pragma unroll
            for (int tc = 0; tc < 8; ++tc)
                #pragma unroll
                for (int r = 0; r < 4; ++r) {
                    int m = row0 + wrow + tr*16 + lq*4 + r;
                    int b = m >> 11;
                    int s = m & (SEQ - 1);
                    int dd = (tc*16 + lr) & 63;
                    int hh = base_hh + (tc >> 2);
                    float v = acc[tr][tc][r];
                    float o = __shfl_xor(v, 1, 64);
                    float2 cs = rope[s*32 + (dd >> 1)];
                    float rv = (dd & 1) ? fmaf(o, cs.y,  v * cs.x)
                                        : fmaf(-o, cs.y, v * cs.x);
                    out[((size_t)((b*NUM_HEADS + hh)*SEQ + s))*DK + dd] =
                        f2bu(rv * qscale);
                }
    }
}

// ---------------------------------------------------------------------------
// Out projection, 128x64 tiles (512 blocks = 2/CU), global_load_lds staging.
// out[m,n] = sum_k attnb[m,k]*Wo[n,k], fp32.  grid (16, 32).
// ---------------------------------------------------------------------------
__global__ __launch_bounds__(256)
void gemm_out(const ushort* __restrict__ A, const ushort* __restrict__ W,
              float* __restrict__ out)
{
    __shared__ ushort As[128][32];
    __shared__ ushort Bs[64][32];

    const int t = threadIdx.x;
    const int w = t >> 6;
    const int L = t & 63;
    const int lr = L & 15;
    const int lq = L >> 4;
    const int row0 = blockIdx.y * 128;
    const int col0 = blockIdx.x * 64;
    const int wrow = w * 32;

    floatx4 acc[2][4];
    #pragma unroll
    for (int i = 0; i < 2; ++i)
        #pragma unroll
        for (int j = 0; j < 4; ++j)
            acc[i][j] = (floatx4){0.f,0.f,0.f,0.f};

    const int rr = t >> 2, ko = (t & 3) * 8;
    const ushort* ga = A + (size_t)(row0 + rr) * DM + ko;
    const ushort* gb = W + (size_t)(col0 + rr) * DM + ko;

    for (int k0 = 0; k0 < DM; k0 += 32) {
        __syncthreads();
        gl16(ga + k0,                 &As[rr][ko]);
        gl16(ga + k0 + (size_t)64*DM, &As[rr + 64][ko]);
        gl16(gb + k0,                 &Bs[rr][ko]);
        __syncthreads();

        bf16x8 aF0 = *(const bf16x8*)&As[wrow + lr][lq*8];
        bf16x8 aF1 = *(const bf16x8*)&As[wrow + 16 + lr][lq*8];
        #pragma unroll
        for (int tc = 0; tc < 4; ++tc) {
            bf16x8 bF = *(const bf16x8*)&Bs[tc*16 + lr][lq*8];
            acc[0][tc] = __builtin_amdgcn_mfma_f32_16x16x32_bf16(aF0, bF, acc[0][tc], 0, 0, 0);
            acc[1][tc] = __builtin_amdgcn_mfma_f32_16x16x32_bf16(aF1, bF, acc[1][tc], 0, 0, 0);
        }
    }

    #pragma unroll
    for (int tr = 0; tr < 2; ++tr)
        #pragma unroll
        for (int tc = 0; tc < 4; ++tc)
            #pragma unroll
            for (int r = 0; r < 4; ++r) {
                int m = row0 + wrow + tr*16 + lq*4 + r;
                int c = col0 + tc*16 + lr;
                out[(size_t)m * DM + c] = acc[tr][tc][r];
            }
}

// ---------------------------------------------------------------------------
// Flash attention, bf16 MFMA, no-max softmax, transposed QK (S^T = K·Q^T).
// Work split into near-uniform chunks of <=8 key-tiles: nch(qt) = qt/8+1.
// grid.x = 80 per (h,b) -> 2560 blocks (2.0 scheduling rounds, dynamic
// balance). qt<8: direct write. qt>=8: bf16 O-partial + fp32 l per chunk
// into fixed 4 slots/(qt,bh); combine() reduces.
// ---------------------------------------------------------------------------
__global__ __launch_bounds__(256)
void attn_mfma(const ushort* __restrict__ Qb, const ushort* __restrict__ Kb,
               const ushort* __restrict__ VT, ushort* __restrict__ attnb,
               ushort* __restrict__ Opart, float* __restrict__ lpart)
{
    __shared__ ushort Ks[64][72];      // [key][dim]
    __shared__ ushort Vs[64][72];      // [dim][key]
    __shared__ ushort Ps[4][16][72];   // per-wave P[q][key]

    const int t = threadIdx.x;
    const int w = t >> 6;
    const int L = t & 63;
    const int lr = L & 15, lq = L >> 4;
    const int h  = blockIdx.y;
    const int b  = blockIdx.z;

    // chunk mapping: bx 0..79
    int qt, chunk, nch;
    {
        const int bx = blockIdx.x;
        if (bx < 8)       { qt = bx;              chunk = 0;     nch = 1; }
        else if (bx < 24) { int i = bx - 8;  qt = 8  + (i>>1); chunk = i&1;        nch = 2; }
        else if (bx < 48) { int i = bx - 24; int q3 = i/3; qt = 16 + q3; chunk = i - q3*3; nch = 3; }
        else              { int i = bx - 48; qt = 24 + (i>>2); chunk = i&3;        nch = 4; }
    }
    const int nt = qt + 1;
    const int t0 = (nt * chunk) / nch;
    const int t1 = (nt * (chunk + 1)) / nch;
    const int q0 = qt * 64;
    const int qw = q0 + w * 16;
    const size_t qkbase = (size_t)(b*NUM_HEADS + h) * SEQ * DK;

    bf16x8 qF0, qF1;
    {
        const ushort* qp = Qb + qkbase + (size_t)(qw + lr) * DK + lq*8;
        qF0 = *(const bf16x8*)qp;
        qF1 = *(const bf16x8*)(qp + 32);
    }

    floatx4 O[4];
    #pragma unroll
    for (int g = 0; g < 4; ++g) O[g] = (floatx4){0.f,0.f,0.f,0.f};
    float l_lane = 0.f;

    // staging: 64x64 K (8 KB) + 64x64 V^T (8 KB); 2 uint4 each per thread
    const int sr = t >> 3, sc = (t & 7) * 8;
    const ushort* kp0 = Kb + qkbase + (size_t)sr * DK + sc;
    const ushort* vp0 = VT + ((size_t)(h*DK + sr)) * BS + b*SEQ + sc;

    for (int tile = t0; tile < t1; ++tile) {
        const int kb = tile * 64;
        __syncthreads();
        {
            uint4 k0v = *(const uint4*)(kp0 + (size_t)kb * DK);
            uint4 k1v = *(const uint4*)(kp0 + (size_t)(kb + 32) * DK);
            uint4 v0v = *(const uint4*)(vp0 + kb);
            uint4 v1v = *(const uint4*)(vp0 + (size_t)32 * BS + kb);
            *(uint4*)&Ks[sr][sc]      = k0v;
            *(uint4*)&Ks[sr + 32][sc] = k1v;
            *(uint4*)&Vs[sr][sc]      = v0v;
            *(uint4*)&Vs[sr + 32][sc] = v1v;
        }
        __syncthreads();

        const bool lastt = (tile == nt - 1);
        const int lim = qw + lr - kb;          // key offset <= lim is unmasked

        #pragma unroll
        for (int g = 0; g < 4; ++g) {
            floatx4 s = (floatx4){0.f,0.f,0.f,0.f};
            bf16x8 kf0 = *(const bf16x8*)&Ks[g*16 + lr][lq*8];
            bf16x8 kf1 = *(const bf16x8*)&Ks[g*16 + lr][32 + lq*8];
            // S^T = K·Q^T: lane -> q = qw+lr (col), key = kb+g*16+lq*4+r (row)
            s = __builtin_amdgcn_mfma_f32_16x16x32_bf16(kf0, qF0, s, 0, 0, 0);
            s = __builtin_amdgcn_mfma_f32_16x16x32_bf16(kf1, qF1, s, 0, 0, 0);
            float p0, p1, p2, p3;
            if (lastt) {
                const int kbase = g*16 + lq*4;
                p0 = (kbase + 0 <= lim) ? exp2f(s[0]) : 0.f;
                p1 = (kbase + 1 <= lim) ? exp2f(s[1]) : 0.f;
                p2 = (kbase + 2 <= lim) ? exp2f(s[2]) : 0.f;
                p3 = (kbase + 3 <= lim) ? exp2f(s[3]) : 0.f;
            } else {
                p0 = exp2f(s[0]); p1 = exp2f(s[1]);
                p2 = exp2f(s[2]); p3 = exp2f(s[3]);
            }
            l_lane += (p0 + p1) + (p2 + p3);
            uint2 pk;
            pk.x = packbf(p0, p1);
            pk.y = packbf(p2, p3);
            *(uint2*)&Ps[w][lr][g*16 + lq*4] = pk;
        }
        asm volatile("s_waitcnt lgkmcnt(0)" ::: "memory");

        #pragma unroll
        for (int c = 0; c < 2; ++c) {
            bf16x8 pF = *(const bf16x8*)&Ps[w][lr][c*32 + lq*8];
            #pragma unroll
            for (int g2 = 0; g2 < 4; ++g2) {
                bf16x8 vf = *(const bf16x8*)&Vs[g2*16 + lr][c*32 + lq*8];
                O[g2] = __builtin_amdgcn_mfma_f32_16x16x32_bf16(pF, vf, O[g2], 0, 0, 0);
            }
        }
    }

    // l for q=qw+lr: sum across the 4 lq lanes sharing lr
    l_lane += __shfl_xor(l_lane, 16, 64);
    l_lane += __shfl_xor(l_lane, 32, 64);

    if (nch == 1) {
        #pragma unroll
        for (int r = 0; r < 4; ++r) {
            float lv = __shfl(l_lane, lq*4 + r, 64);   // l for q row lq*4+r
            float li = 1.f / lv;
            int s = qw + lq*4 + r;
            #pragma unroll
            for (int g2 = 0; g2 < 4; ++g2)
                attnb[((size_t)(b*SEQ + s))*DM + h*DK + g2*16 + lr] = f2bu(O[g2][r] * li);
        }
    } else {
        const int slot = ((b*NUM_HEADS + h)*24 + (qt - 8))*4 + chunk;
        ushort* Op = Opart + (size_t)slot * 4096;
        #pragma unroll
        for (int r = 0; r < 4; ++r) {
            int ql = w*16 + lq*4 + r;
            #pragma unroll
            for (int g2 = 0; g2 < 4; ++g2)
                Op[ql*64 + g2*16 + lr] = f2bu(O[g2][r]);
        }
        if (lq == 0) lpart[(size_t)slot*64 + w*16 + lr] = l_lane;
    }
}

// ---------------------------------------------------------------------------
// Combine: for qt>=8, O = (sum_c O_c)/(sum_c l_c) -> attnb bf16.
// grid 768 = 32 (b,h) x 24 qt.
// ---------------------------------------------------------------------------
__global__ __launch_bounds__(256)
void combine(const ushort* __restrict__ Opart, const float* __restrict__ lpart,
             ushort* __restrict__ attnb)
{
    int gx = blockIdx.x;
    int qti = gx % 24, bh = gx / 24;
    int h = bh & 15, b = bh >> 4;
    int qt = 8 + qti;
    int nch = (qt >> 3) + 1;          // 2..4
    int tid = threadIdx.x;
    int row = tid >> 2, c0 = (tid & 3) * 16;
    const int base_slot = (bh*24 + qti)*4;

    float acc[16];
    #pragma unroll
    for (int e = 0; e < 16; ++e) acc[e] = 0.f;
    float l = 0.f;

    for (int c = 0; c < nch; ++c) {
        const ushort* Op = Opart + (size_t)(base_slot + c)*4096 + row*64 + c0;
        uint4 u0 = *(const uint4*)(Op);
        uint4 u1 = *(const uint4*)(Op + 8);
        const ushort* h0 = (const ushort*)&u0;
        const ushort* h1 = (const ushort*)&u1;
        #pragma unroll
        for (int e = 0; e < 8; ++e) { acc[e]   += bu2f(h0[e]); }
        #pragma unroll
        for (int e = 0; e < 8; ++e) { acc[8+e] += bu2f(h1[e]); }
        l += lpart[(size_t)(base_slot + c)*64 + row];
    }
    float li = 1.f / l;
    int s = qt*64 + row;
    ushort* dst = attnb + ((size_t)(b*SEQ + s))*DM + h*DK + c0;
    #pragma unroll
    for (int e = 0; e < 16; ++e) dst[e] = f2bu(acc[e] * li);
}

// ---------------------------------------------------------------------------
extern "C" void kernel_launch(void* const* d_in, const int* in_sizes, int n_in,
                              void* d_out, int out_size, void* d_ws, size_t ws_size,
                              hipStream_t stream) {
    const float* x   = (const float*)d_in[0];
    const float* Wq  = (const float*)d_in[1];
    const float* Wk  = (const float*)d_in[2];
    const float* Wv  = (const float*)d_in[3];
    const float* Wo  = (const float*)d_in[4];
    const int*   pos = (const int*)d_in[5];
    float* out = (float*)d_out;

    const size_t MB = 1u << 20;
    char* ws = (char*)d_ws;
    // xb/Wqkb/Wvb dead after projections; Opart (24 MB) aliases them.
    ushort* xb    = (ushort*)(ws);             //  8 MB  [4096,1024]
    ushort* Wqkb  = (ushort*)(ws +  8*MB);     //  4 MB  [Wq;Wk]
    ushort* Wvb   = (ushort*)(ws + 12*MB);     //  2 MB
    ushort* Opart = (ushort*)(ws);             // 24 MB  [3072 slots][64][64] bf16
    float*  lpart = (float*)(ws + 24*MB);      //  768 KB
    ushort* Qb    = (ushort*)(ws + 25*MB);     //  8 MB  [b,h,s,64] (Q scaled)
    ushort* Kb    = (ushort*)(ws + 33*MB);     //  8 MB  (== Qb + 4194304)
    ushort* VT    = (ushort*)(ws + 41*MB);     //  8 MB  [h*64+dv, b*2048+s]
    ushort* attnb = (ushort*)(ws + 49*MB);     //  8 MB  [4096,1024]
    float2* ropeT = (float2*)(ws + 57*MB);     //  0.5 MB
    ushort* Wob   = (ushort*)(ws + 58*MB);     //  2 MB  (survives to out-GEMM)

    dim3 blk(256);
    castall<<<4352, blk, 0, stream>>>(x, Wq, Wk, Wv, Wo, pos,
                                      xb, Wqkb, Wvb, Wob, ropeT);

    proj_fused<<<768, blk, 0, stream>>>(xb, Wqkb, Wvb, Qb, VT, ropeT);

    attn_mfma<<<dim3(80, NUM_HEADS, BATCHN), blk, 0, stream>>>(Qb, Kb, VT, attnb,
                                                               Opart, lpart);
    combine<<<768, blk, 0, stream>>>(Opart, lpart, attnb);

    gemm_out<<<dim3(16,32), blk, 0, stream>>>(attnb, Wob, out);
}